// Round 12
// baseline (28.754 us; speedup 1.0000x reference)
//
#include <hip/hip_runtime.h>

// Cone-beam projection: D=W=H=128 volume, 180x180 detector, BATCH=4.
// out[b][0][i][j] = dx(b,i,j) * sum_{k=0..127} trilinear(vol, ray(b,i,j,k))
//
// Index-space ray, linear in k:
//   iz(k) = izb + k*izs  (D axis, stride 2^14)
//   iy(k) = k*(127/128)  (W axis, never OOB)
//   ix(k) = ixb + k*ixs  (H axis, stride 1)
// Per-axis masked weights reproduce the reference's zero padding exactly.
//
// SHAPE: R4-proven: 256-thr blocks = 32 adjacent-j px x 8 k-threads; 4050
// blocks (~2x residency); coprime swizzle for CU balance.
//
// ROUND-12 LEVER: R11's dual 8-k streams sat in divergent if-blocks, so the
// compiler could NOT batch the two streams' loads past the first s_waitcnt.
// This version is BRANCH-FREE: both streams always execute; k is clamped
// into its stream interval (addresses stay safe via existing x/z clamps and
// y0 in [0,126] for k in [0,127]) and a validity multiplier zeroes the
// contribution. Body is ordered addresses -> 8 loads -> weights/FMA so all
// 8 gathers issue before the first wait (true 8-deep per-wave MLP).
//
// Negative results (do not revisit): per-lane 3-phase interior split (R5);
// 64px/512-thr blocks (R5/R7); per-call pad staging (R8); XCD k-partition +
// reduce (R9); unroll-4 on short trips (R10); divergent dual-stream (R11).

#define RES 180
#define NPIX (4 * RES * RES)       // 129600
#define PPB 32
#define NCHUNK (NPIX / PPB)        // 4050
#define CHUNK_STRIDE 1013          // prime, coprime to 4050

typedef struct __attribute__((packed, aligned(4))) { float x, y; } f2u;

__global__ __launch_bounds__(256) void proj_kernel(
    const float* __restrict__ vol, const float* __restrict__ poses,
    const float* __restrict__ spacing, float* __restrict__ out) {
  const int tid = threadIdx.x;
  const int lp  = tid & 31;       // pixel slot
  const int ks  = tid >> 5;       // k-thread 0..7
  const int chunk = (int)(((long long)blockIdx.x * CHUNK_STRIDE) % NCHUNK);
  const int gpix = chunk * PPB + lp;

  const int b   = gpix / (RES * RES);
  const int rem = gpix - b * (RES * RES);
  const int i   = rem / RES;
  const int j   = rem - i * RES;

  const float ex = poses[b * 3 + 0];
  const float ey = poses[b * 3 + 1];
  const float ez = poses[b * 3 + 2];

  const float Ix = ((float)i - 90.0f) - ex;
  const float Iy = -ey;                // ~ +300
  const float Iz = ((float)j - 90.0f) - ez;

  const float c     = 63.5f / 64.0f;   // exact in fp32
  const float invIy = 1.0f / Iy;

  const float izb = fmaf(ex + Ix, c, 63.5f);
  const float izs = Ix * invIy * c;
  const float ixb = fmaf(ez + Iz, c, 63.5f);
  const float ixs = Iz * invIy * c;

  // ---- global valid k-interval: ix,iz in (-1,128), k in [0,128) ----
  float ka = 0.0f, kb = 128.0f;
  if (ixs > 1e-12f)       { ka = fmaxf(ka, (-1.0f - ixb) / ixs); kb = fminf(kb, (128.0f - ixb) / ixs); }
  else if (ixs < -1e-12f) { ka = fmaxf(ka, (128.0f - ixb) / ixs); kb = fminf(kb, (-1.0f - ixb) / ixs); }
  else if (ixb <= -1.0f || ixb >= 128.0f) { kb = ka; }
  if (izs > 1e-12f)       { ka = fmaxf(ka, (-1.0f - izb) / izs); kb = fminf(kb, (128.0f - izb) / izs); }
  else if (izs < -1e-12f) { ka = fmaxf(ka, (128.0f - izb) / izs); kb = fminf(kb, (-1.0f - izb) / izs); }
  else if (izb <= -1.0f || izb >= 128.0f) { kb = ka; }
  ka = fmaxf(ka, 0.0f);
  kb = fminf(kb, 128.0f);
  const int kai = (int)ceilf(ka);
  const int kbi = (int)ceilf(kb);   // masks keep edges exact

  // ---- two mirrored 8-k chunks per thread (correlated lengths) ----
  const int c1 = ks;              // k in [8c1, 8c1+8)
  const int c2 = 15 - ks;         // k in [8c2, 8c2+8)
  const int a1 = max(kai, 8 * c1), b1 = min(kbi, 8 * c1 + 8);
  const int a2 = max(kai, 8 * c2), b2 = min(kbi, 8 * c2 + 8);
  const int n1 = max(0, b1 - a1);
  const int n2 = max(0, b2 - a2);
  const int nt = max(n1, n2);

  float sum = 0.0f;

  for (int t = 0; t < nt; ++t) {
    // clamped k per stream: address-safe even when the stream is exhausted
    const int k1 = max(a1 + min(t, n1 - 1), 0);
    const int k2 = max(a2 + min(t, n2 - 1), 0);
    const float msk1 = (t < n1) ? 1.0f : 0.0f;
    const float msk2 = (t < n2) ? 1.0f : 0.0f;

    // ---------- phase A: addresses for both streams ----------
    const float kf1 = (float)k1;
    const float ix1 = fmaf(kf1, ixs, ixb);
    const float iy1 = kf1 * c;
    const float iz1 = fmaf(kf1, izs, izb);
    const float fx1 = floorf(ix1), fy1 = floorf(iy1), fz1 = floorf(iz1);
    const int x01 = (int)fx1, y01 = (int)fy1, z01 = (int)fz1;
    const int xb1 = min(max(x01, 0), 126);
    const int zc01 = min(max(z01, 0), 127), zc11 = min(max(z01 + 1, 0), 127);
    const float* base1 = vol + ((zc01 << 14) + (y01 << 7) + xb1);
    const int dz1 = (zc11 - zc01) << 14;

    const float kf2 = (float)k2;
    const float ix2 = fmaf(kf2, ixs, ixb);
    const float iy2 = kf2 * c;
    const float iz2 = fmaf(kf2, izs, izb);
    const float fx2 = floorf(ix2), fy2 = floorf(iy2), fz2 = floorf(iz2);
    const int x02 = (int)fx2, y02 = (int)fy2, z02 = (int)fz2;
    const int xb2 = min(max(x02, 0), 126);
    const int zc02 = min(max(z02, 0), 127), zc12 = min(max(z02 + 1, 0), 127);
    const float* base2 = vol + ((zc02 << 14) + (y02 << 7) + xb2);
    const int dz2 = (zc12 - zc02) << 14;

    // ---------- phase B: all 8 loads ----------
    const f2u A00 = *(const f2u*)(base1);
    const f2u A01 = *(const f2u*)(base1 + 128);
    const f2u A10 = *(const f2u*)(base1 + dz1);
    const f2u A11 = *(const f2u*)(base1 + dz1 + 128);
    const f2u B00 = *(const f2u*)(base2);
    const f2u B01 = *(const f2u*)(base2 + 128);
    const f2u B10 = *(const f2u*)(base2 + dz2);
    const f2u B11 = *(const f2u*)(base2 + dz2 + 128);

    // ---------- phase C: weights + FMA chains ----------
    {
      const float wx1 = ix1 - fx1, wy1 = iy1 - fy1, wz1 = iz1 - fz1;
      const float wx0 = 1.0f - wx1, wy0 = 1.0f - wy1, wz0 = 1.0f - wz1;
      const float vx0 = ((unsigned)x01       < 128u) ? wx0 : 0.0f;
      const float vx1 = ((unsigned)(x01 + 1) < 128u) ? wx1 : 0.0f;
      const float vz0 = (((unsigned)z01       < 128u) ? wz0 : 0.0f) * msk1;
      const float vz1 = (((unsigned)(z01 + 1) < 128u) ? wz1 : 0.0f) * msk1;
      const bool inx = (x01 == xb1);
      const float wlo = inx ? vx0 : vx1;
      const float whi = inx ? vx1 : vx0;
      const float s00 = fmaf(whi, A00.y, wlo * A00.x);
      const float s01 = fmaf(whi, A01.y, wlo * A01.x);
      const float s10 = fmaf(whi, A10.y, wlo * A10.x);
      const float s11 = fmaf(whi, A11.y, wlo * A11.x);
      const float s0  = fmaf(wy1, s01, wy0 * s00);
      const float s1  = fmaf(wy1, s11, wy0 * s10);
      sum = fmaf(vz0, s0, sum);
      sum = fmaf(vz1, s1, sum);
    }
    {
      const float wx1 = ix2 - fx2, wy1 = iy2 - fy2, wz1 = iz2 - fz2;
      const float wx0 = 1.0f - wx1, wy0 = 1.0f - wy1, wz0 = 1.0f - wz1;
      const float vx0 = ((unsigned)x02       < 128u) ? wx0 : 0.0f;
      const float vx1 = ((unsigned)(x02 + 1) < 128u) ? wx1 : 0.0f;
      const float vz0 = (((unsigned)z02       < 128u) ? wz0 : 0.0f) * msk2;
      const float vz1 = (((unsigned)(z02 + 1) < 128u) ? wz1 : 0.0f) * msk2;
      const bool inx = (x02 == xb2);
      const float wlo = inx ? vx0 : vx1;
      const float whi = inx ? vx1 : vx0;
      const float s00 = fmaf(whi, B00.y, wlo * B00.x);
      const float s01 = fmaf(whi, B01.y, wlo * B01.x);
      const float s10 = fmaf(whi, B10.y, wlo * B10.x);
      const float s11 = fmaf(whi, B11.y, wlo * B11.x);
      const float s0  = fmaf(wy1, s01, wy0 * s00);
      const float s1  = fmaf(wy1, s11, wy0 * s10);
      sum = fmaf(vz0, s0, sum);
      sum = fmaf(vz1, s1, sum);
    }
  }

  __shared__ float part[256];
  part[tid] = sum;
  __syncthreads();

  if (tid < PPB) {
    float tot = 0.0f;
#pragma unroll
    for (int s = 0; s < 8; ++s) tot += part[tid + 32 * s];
    const float ax = Ix * invIy * spacing[0];
    const float az = Iz * invIy * spacing[2];
    const float sy = spacing[1];
    out[gpix] = tot * sqrtf(fmaf(ax, ax, fmaf(az, az, sy * sy)));
  }
}

extern "C" void kernel_launch(void* const* d_in, const int* in_sizes, int n_in,
                              void* d_out, int out_size, void* d_ws, size_t ws_size,
                              hipStream_t stream) {
  const float* vol     = (const float*)d_in[0];   // [1,1,128,128,128] fp32
  const float* poses   = (const float*)d_in[1];   // [4,3] fp32
  const float* spacing = (const float*)d_in[2];   // [3] fp32
  float* out = (float*)d_out;                     // [4,1,180,180] fp32

  proj_kernel<<<NCHUNK, 256, 0, stream>>>(vol, poses, spacing, out);
}

// Round 13
// 26.004 us; speedup vs baseline: 1.1058x; 1.1058x over previous
//
#include <hip/hip_runtime.h>

// Cone-beam projection: D=W=H=128 volume, 180x180 detector, BATCH=4.
// out[b][0][i][j] = dx(b,i,j) * sum_{k=0..127} trilinear(vol, ray(b,i,j,k))
//
// Index-space ray, linear in k:
//   iz(k) = izb + k*izs  (D axis, stride 2^14)
//   iy(k) = k*(127/128)  (W axis, never OOB)
//   ix(k) = ixb + k*ixs  (H axis, stride 1)
// Per-axis masked weights reproduce the reference's zero padding exactly.
//
// ROUND-13 STRUCTURE: SINGLE-WAVE BLOCKS (64 thr = 16 adjacent-j px x 4
// k-threads), zero barriers/LDS. R11's blocks coupled 4 waves at a terminal
// __syncthreads -> CU slot freed only when the slowest wave finished; this
// makes every wave independently schedulable/replaceable (8100 blocks, ~4x
// wave-granular residency). Each k-thread owns TWO MIRRORED 16-k chunks
// (c, 7-c: near/far mirror -> balanced lengths, R11-proven) as R11-style
// divergent-if dual streams (branch-free predication regressed, R12).
// Cross-k reduce = 2 shfl_xor; lanes 0..15 write out.
//
// Negative results (do not revisit): per-lane 3-phase interior split (R5);
// 64px/512-thr blocks (R5/R7); per-call pad staging (R8: L2 dirty per
// replay); XCD k-partition + reduce kernel (R9); unroll-4 on short trips
// (R10); branch-free predicated dual-stream (R12: +VALU, no gain).

#define RES 180
#define NPIX (4 * RES * RES)       // 129600
#define PPB 16
#define NCHUNK (NPIX / PPB)        // 8100 = 2^2 * 3^4 * 5^2
#define CHUNK_STRIDE 1013          // prime, coprime to 8100

typedef struct __attribute__((packed, aligned(4))) { float x, y; } f2u;

__global__ __launch_bounds__(64) void proj_kernel(
    const float* __restrict__ vol, const float* __restrict__ poses,
    const float* __restrict__ spacing, float* __restrict__ out) {
  const int tid = threadIdx.x;    // 0..63, one wave
  const int lp  = tid & 15;       // pixel slot (adjacent j)
  const int ks  = tid >> 4;       // k-thread 0..3
  const int chunk = (int)(((long long)blockIdx.x * CHUNK_STRIDE) % NCHUNK);
  const int gpix = chunk * PPB + lp;

  const int b   = gpix / (RES * RES);
  const int rem = gpix - b * (RES * RES);
  const int i   = rem / RES;
  const int j   = rem - i * RES;

  const float ex = poses[b * 3 + 0];
  const float ey = poses[b * 3 + 1];
  const float ez = poses[b * 3 + 2];

  const float Ix = ((float)i - 90.0f) - ex;
  const float Iy = -ey;                // ~ +300
  const float Iz = ((float)j - 90.0f) - ez;

  const float c     = 63.5f / 64.0f;   // exact in fp32
  const float invIy = 1.0f / Iy;

  const float izb = fmaf(ex + Ix, c, 63.5f);
  const float izs = Ix * invIy * c;
  const float ixb = fmaf(ez + Iz, c, 63.5f);
  const float ixs = Iz * invIy * c;

  // ---- global valid k-interval: ix,iz in (-1,128), k in [0,128) ----
  float ka = 0.0f, kb = 128.0f;
  if (ixs > 1e-12f)       { ka = fmaxf(ka, (-1.0f - ixb) / ixs); kb = fminf(kb, (128.0f - ixb) / ixs); }
  else if (ixs < -1e-12f) { ka = fmaxf(ka, (128.0f - ixb) / ixs); kb = fminf(kb, (-1.0f - ixb) / ixs); }
  else if (ixb <= -1.0f || ixb >= 128.0f) { kb = ka; }
  if (izs > 1e-12f)       { ka = fmaxf(ka, (-1.0f - izb) / izs); kb = fminf(kb, (128.0f - izb) / izs); }
  else if (izs < -1e-12f) { ka = fmaxf(ka, (128.0f - izb) / izs); kb = fminf(kb, (-1.0f - izb) / izs); }
  else if (izb <= -1.0f || izb >= 128.0f) { kb = ka; }
  ka = fmaxf(ka, 0.0f);
  kb = fminf(kb, 128.0f);
  const int kai = (int)ceilf(ka);
  const int kbi = (int)ceilf(kb);   // masks keep edges exact

  // ---- two mirrored 16-k chunks per k-thread (correlated lengths) ----
  const int c1 = ks;              // k in [16c1, 16c1+16)
  const int c2 = 7 - ks;          // k in [16c2, 16c2+16)
  const int a1 = max(kai, 16 * c1), b1 = min(kbi, 16 * c1 + 16);
  const int a2 = max(kai, 16 * c2), b2 = min(kbi, 16 * c2 + 16);
  const int n1 = max(0, b1 - a1);
  const int n2 = max(0, b2 - a2);
  const int nt = max(n1, n2);

  float sum = 0.0f;

#define BODY(kk)                                                               \
  {                                                                            \
    const int k = (kk);                                                        \
    const float kf = (float)k;                                                 \
    const float ix = fmaf(kf, ixs, ixb);                                       \
    const float iy = kf * c;                                                   \
    const float iz = fmaf(kf, izs, izb);                                       \
    const float fx = floorf(ix), fy = floorf(iy), fz = floorf(iz);             \
    const int x0 = (int)fx, y0 = (int)fy, z0 = (int)fz;                        \
    const float wx1 = ix - fx, wy1 = iy - fy, wz1 = iz - fz;                   \
    const float wx0 = 1.0f - wx1, wy0 = 1.0f - wy1, wz0 = 1.0f - wz1;          \
    const float vx0 = ((unsigned)x0       < 128u) ? wx0 : 0.0f;                \
    const float vx1 = ((unsigned)(x0 + 1) < 128u) ? wx1 : 0.0f;                \
    const float vz0 = ((unsigned)z0       < 128u) ? wz0 : 0.0f;                \
    const float vz1 = ((unsigned)(z0 + 1) < 128u) ? wz1 : 0.0f;                \
    const int xb2 = min(max(x0, 0), 126);                                      \
    const bool inx = (x0 == xb2);                                              \
    const float wlo = inx ? vx0 : vx1;                                         \
    const float whi = inx ? vx1 : vx0;                                         \
    const int zc0 = min(max(z0, 0), 127), zc1 = min(max(z0 + 1, 0), 127);      \
    const float* base = vol + ((zc0 << 14) + (y0 << 7) + xb2);                 \
    const int dz = (zc1 - zc0) << 14;                                          \
    const f2u v00 = *(const f2u*)(base);                                       \
    const f2u v01 = *(const f2u*)(base + 128);                                 \
    const f2u v10 = *(const f2u*)(base + dz);                                  \
    const f2u v11 = *(const f2u*)(base + dz + 128);                            \
    const float s00 = fmaf(whi, v00.y, wlo * v00.x);                           \
    const float s01 = fmaf(whi, v01.y, wlo * v01.x);                           \
    const float s10 = fmaf(whi, v10.y, wlo * v10.x);                           \
    const float s11 = fmaf(whi, v11.y, wlo * v11.x);                           \
    const float s0  = fmaf(wy1, s01, wy0 * s00);                               \
    const float s1  = fmaf(wy1, s11, wy0 * s10);                               \
    sum = fmaf(vz0, s0, sum);                                                  \
    sum = fmaf(vz1, s1, sum);                                                  \
  }

  for (int t = 0; t < nt; ++t) {
    if (t < n1) BODY(a1 + t)
    if (t < n2) BODY(a2 + t)
  }
#undef BODY

  // cross-k reduce over lanes {lp, lp+16, lp+32, lp+48}: butterfly on bits 4,5
  sum += __shfl_xor(sum, 16);
  sum += __shfl_xor(sum, 32);

  if (ks == 0) {
    const float ax = Ix * invIy * spacing[0];
    const float az = Iz * invIy * spacing[2];
    const float sy = spacing[1];
    out[gpix] = sum * sqrtf(fmaf(ax, ax, fmaf(az, az, sy * sy)));
  }
}

extern "C" void kernel_launch(void* const* d_in, const int* in_sizes, int n_in,
                              void* d_out, int out_size, void* d_ws, size_t ws_size,
                              hipStream_t stream) {
  const float* vol     = (const float*)d_in[0];   // [1,1,128,128,128] fp32
  const float* poses   = (const float*)d_in[1];   // [4,3] fp32
  const float* spacing = (const float*)d_in[2];   // [3] fp32
  float* out = (float*)d_out;                     // [4,1,180,180] fp32

  proj_kernel<<<NCHUNK, 64, 0, stream>>>(vol, poses, spacing, out);
}